// Round 5
// baseline (571.815 us; speedup 1.0000x reference)
//
#include <hip/hip_runtime.h>
#include <stdint.h>

// FFN: x[16384,1024] -> relu(x@W1^T+b1)[16384,4096] -> q_e4m3 -> @W2^T+b2 -> q_e5m10
// Round 7: A-operand direct global->register (skip LDS for A). Rounds 5/6 proved
// the per-tile cost (4600cy) is schedule-invariant: serial sum of MFMA floor
// (2483cy/SIMD) + LDS traffic (192KB reads + 64KB writes ~= 2000cy). Fix: shrink
// the LDS term. A fragments are fragment-shaped in global memory (lane fr = row,
// kq = 16B k-chunk); load per-lane b128, pipelined 2 phases ahead via a 4-slot
// static register rotation (phase p consumes slot p, loads slot (p+2)&3; zero
// register moves). A rows shared by 4 wc-waves -> L1/L2 hits. LDS keeps only B:
// 64KB reads + 32KB writes per tile (~900cy), footprint 128->64KB.
// gl16 cluster pinned with sched_barrier(0); tile-end vmcnt(8) drains B-stages
// (A slots 0,1 = the only 8 newer VMEM ops). Numerics bit-identical.
// G1 epilogue: two 128-row half-tile transposes through the 64KB buffer.

#define M_TOT 16384
#define D_DIM 1024
#define H_DIM 4096

typedef _Float16 f16x8 __attribute__((ext_vector_type(8)));
typedef _Float16 f16x4 __attribute__((ext_vector_type(4)));
typedef float f32x4 __attribute__((ext_vector_type(4)));

// global -> LDS direct copy, 16B per lane. LDS dest = wave-uniform base + lane*16.
__device__ __forceinline__ void gl16(const void* g, void* l) {
    __builtin_amdgcn_global_load_lds(
        (const __attribute__((address_space(1))) unsigned int*)(uintptr_t)g,
        (__attribute__((address_space(3))) unsigned int*)(unsigned int)(uintptr_t)l,
        16, 0, 0);
}

// e4m3 quantize (reference float_quantize exp=4 man=3: bias=7, min normal exp -6,
// subnormal quantum 2^-9, RNE, overflow->inf unreachable here: |x| << 240).
__device__ __forceinline__ float q_e4m3_any(float x) {
    uint32_t t = __float_as_uint(x);
    uint32_t s = t & 0x80000000u;
    uint32_t m = t & 0x7fffffffu;
    uint32_t tn = (m + 0x7ffffu + ((m >> 20) & 1u)) & 0xfff00000u;
    float qn = __uint_as_float(tn | s);
    float qs = rintf(x * 512.0f) * 0.001953125f;   // RNE, exact scales
    return __uint_as_float(m) < 0.015625f ? qs : qn;
}

// positive-input fast path (post-relu): no sign handling
__device__ __forceinline__ _Float16 q_e4m3_pos(float v) {
    uint32_t t = __float_as_uint(v);
    uint32_t tn = (t + 0x7ffffu + ((t >> 20) & 1u)) & 0xfff00000u;
    float qn = __uint_as_float(tn);
    float qs = rintf(v * 512.0f) * 0.001953125f;
    return (_Float16)(v < 0.015625f ? qs : qn);
}

// ---- pre-pass: fp32 -> f16 (RNE), vectorized x4 ----
__global__ __launch_bounds__(256) void cvt_f16_kernel(
    const float* __restrict__ in, _Float16* __restrict__ out, int n4)
{
    int i = blockIdx.x * 256 + threadIdx.x;
    if (i >= n4) return;
    float4 v = reinterpret_cast<const float4*>(in)[i];
    f16x4 hv = {(_Float16)v.x, (_Float16)v.y, (_Float16)v.z, (_Float16)v.w};
    reinterpret_cast<f16x4*>(out)[i] = hv;
}

// ---- pre-pass: fp32 -> e4m3 value stored as f16 (exactly representable) ----
__global__ __launch_bounds__(256) void quant_e4m3_kernel(
    const float* __restrict__ in, _Float16* __restrict__ outq, int n4)
{
    int i = blockIdx.x * 256 + threadIdx.x;
    if (i >= n4) return;
    float4 v = reinterpret_cast<const float4*>(in)[i];
    f16x4 q = {(_Float16)q_e4m3_any(v.x), (_Float16)q_e4m3_any(v.y),
               (_Float16)q_e4m3_any(v.z), (_Float16)q_e4m3_any(v.w)};
    reinterpret_cast<f16x4*>(outq)[i] = q;
}

// load one A phase-batch (4 x b128 per lane) into slot s: rows (2*pp,2*pp+1)*16
// of the wave's 128-row panel, k-base b64 (element offset t*64 or (t+1)*64).
#define LOAD_A(s, pp, b64) \
    aq[s][0][0] = *(const f16x8*)(pA + (size_t)((2*(pp))*16) * K + (b64)); \
    aq[s][0][1] = *(const f16x8*)(pA + (size_t)((2*(pp))*16) * K + (b64) + 32); \
    aq[s][1][0] = *(const f16x8*)(pA + (size_t)((2*(pp)+1)*16) * K + (b64)); \
    aq[s][1][1] = *(const f16x8*)(pA + (size_t)((2*(pp)+1)*16) * K + (b64) + 32);

// ---- unified 256x256 GEMM, NT (A[M,K], B[N,K] row-major), f16 MFMA fp32 acc ----
// G1=true : epilogue = +bias, relu, q_e4m3, LDS-transpose, coalesced f16 store
// G1=false: epilogue = +f16(bias), f16-roundtrip, store fp32 (already coalesced)
template<int K, int N, bool G1>
__global__ __launch_bounds__(512) void gemm_ffn(
    const _Float16* __restrict__ A, const _Float16* __restrict__ B,
    const float* __restrict__ bias, void* __restrict__ Cv)
{
    // B only in LDS now: 2 dbuf x [256 rows][64 K] f16 = 64 KiB.
    // Reused as the C half-tile transpose buffer (64 KiB) in the G1 epilogue.
    __shared__ __align__(16) _Float16 smem[32768];
    _Float16* sB = smem;

    const int tid  = threadIdx.x;
    const int lane = tid & 63;
    const int w    = tid >> 6;            // 8 waves: 2(M) x 4(N)
    const int wr   = w >> 2, wc = w & 3;  // per-wave C: 128 rows x 64 cols
    const int fr   = lane & 15, kq = lane >> 4;

    // T1: bijective XCD-chunked block swizzle (nwg % 8 == 0 for both GEMMs)
    constexpr int NBX = N / 256;
    constexpr int NWG = (M_TOT / 256) * NBX;
    constexpr int CPX = NWG / 8;
    int bid = blockIdx.y * NBX + blockIdx.x;
    bid = (bid & 7) * CPX + (bid >> 3);
    const int n0 = (bid % NBX) * 256;
    const int m0 = (bid / NBX) * 256;

    // B staging: thread t covers LDS bytes t*16 of each 8KB round (64 rows x 128B).
    // source pre-swizzle: 16B-slot ^= (row & 7)  (involution, matches read XOR)
    const int srow = tid >> 3;                       // 0..63 row-in-round
    const int sseg = (tid & 7) ^ (srow & 7);         // swizzled 16B slot
    const _Float16* gB = B + (size_t)(n0 + srow) * K + sseg * 8;
    const int ldsw = w * 512;                        // wave offset in a round (f16)
    const size_t R1 = (size_t)64 * K, R2 = (size_t)128 * K, R3 = (size_t)192 * K;

    // B fragment reads: row*64 + ((ks*4+kq) ^ (row&7))*8 ; row&7 == fr&7 always
    const int xorv = fr & 7;
    const int cB0 = (kq ^ xorv) * 8;         // ks=0 slot (elements)
    const int cB1 = ((kq + 4) ^ xorv) * 8;   // ks=1 slot
    const int bRow = wc * 64 + fr;

    // A direct-from-global per-lane base: row = m0 + wr*128 + fr, k-chunk = kq*8
    const _Float16* pA = A + (size_t)(m0 + wr * 128 + fr) * K + kq * 8;

    f32x4 acc[8][4];
#pragma unroll
    for (int i = 0; i < 8; i++)
#pragma unroll
        for (int j = 0; j < 4; j++) acc[i][j] = (f32x4){0.f, 0.f, 0.f, 0.f};

    f16x8 bfr[4][2];
    f16x8 aq[4][2][2];   // 4-slot A pipeline, statically indexed everywhere

    constexpr int NK = K / 64;

    // prologue: stage B(0); pin; load A slots 0,1 (tile0 p0,p1); drain; barrier.
    gl16(gB,      sB + ldsw);
    gl16(gB + R1, sB + 4096 + ldsw);
    gl16(gB + R2, sB + 8192 + ldsw);
    gl16(gB + R3, sB + 12288 + ldsw);
    __builtin_amdgcn_sched_barrier(0);
    LOAD_A(0, 0, 0)
    LOAD_A(1, 1, 0)
    asm volatile("s_waitcnt vmcnt(0)" ::: "memory");
    __builtin_amdgcn_s_barrier();
    asm volatile("" ::: "memory");

    for (int t = 0; t < NK; ++t) {
        const int c = t & 1;
        const _Float16* sBc = sB + c * 16384;
        _Float16* sBn = sB + (c ^ 1) * 16384;
        const bool pref = (t + 1 < NK);
        const size_t t64 = (size_t)t * 64;

        // stage next B tile first (oldest in vmcnt queue), pinned so A-loads
        // cannot be scheduled above it -> tile-end vmcnt(8) provably drains it.
        if (pref) {
            const _Float16* gBn = gB + t64 + 64;
            gl16(gBn,      sBn + ldsw);
            gl16(gBn + R1, sBn + 4096 + ldsw);
            gl16(gBn + R2, sBn + 8192 + ldsw);
            gl16(gBn + R3, sBn + 12288 + ldsw);
            __builtin_amdgcn_sched_barrier(0);
        }

#pragma unroll
        for (int p = 0; p < 4; ++p) {
            // A pipeline: consume slot p, issue slot (p+2)&3 two phases ahead
            if (p == 0) { LOAD_A(2, 2, t64) }
            if (p == 1) { LOAD_A(3, 3, t64) }
            if (p == 2 && pref) { LOAD_A(0, 0, t64 + 64) }
            if (p == 3 && pref) { LOAD_A(1, 1, t64 + 64) }
            if (p == 0) {
#pragma unroll
                for (int j = 0; j < 4; j++) {
                    const _Float16* rb = sBc + (bRow + j * 16) * 64;
                    bfr[j][0] = *(const f16x8*)(rb + cB0);
                    bfr[j][1] = *(const f16x8*)(rb + cB1);
                }
            }
            __builtin_amdgcn_s_setprio(1);
#pragma unroll
            for (int ii = 0; ii < 2; ii++)
#pragma unroll
                for (int j = 0; j < 4; j++) {
                    acc[2*p+ii][j] = __builtin_amdgcn_mfma_f32_16x16x32_f16(
                        aq[p][ii][0], bfr[j][0], acc[2*p+ii][j], 0, 0, 0);
                    acc[2*p+ii][j] = __builtin_amdgcn_mfma_f32_16x16x32_f16(
                        aq[p][ii][1], bfr[j][1], acc[2*p+ii][j], 0, 0, 0);
                }
            __builtin_amdgcn_s_setprio(0);
        }

        // tile end: newest 8 VMEM = A slots 0,1 -> vmcnt(8) retires the 4 gl16
        // (oldest) without draining the A pipeline; barrier frees buf c.
        if (pref) asm volatile("s_waitcnt vmcnt(8)" ::: "memory");
        asm volatile("" ::: "memory");
        __builtin_amdgcn_s_barrier();
        asm volatile("" ::: "memory");
    }

    // epilogue (C frag layout: col = lane&15, row = kq*4 + reg)
    const int col0 = n0 + wc * 64 + fr;
    if constexpr (G1) {
        // two 128-row half-tiles through the 64KB buffer:
        // wr==half waves quantize+ds_write (swizzled), then all 512 threads
        // stream the half out with coalesced f16x8 stores.
        _Float16* Cq = (_Float16*)Cv;
        float bv[4];
#pragma unroll
        for (int j = 0; j < 4; j++) bv[j] = bias[col0 + j * 16];
        const int sub = (fr & 7) * 2;             // byte within 16B slot
        const int slotbase = wc * 8 + (fr >> 3);  // + j*2
        const int rowrel0 = kq * 4;               // + i*16 + r (0..127 in-half)
#pragma unroll
        for (int half = 0; half < 2; ++half) {
            if (wr == half) {
#pragma unroll
                for (int i = 0; i < 8; i++) {
                    const int trow0 = rowrel0 + i * 16;
#pragma unroll
                    for (int r = 0; r < 4; r++) {
                        const int trow = trow0 + r;
                        const int swz = ((kq & 1) * 4 + r) ^ (kq >> 1);  // (trow&7)^((trow>>3)&1)
#pragma unroll
                        for (int j = 0; j < 4; j++) {
                            float v = fmaxf(acc[i][j][r] + bv[j], 0.0f);
                            _Float16 q = q_e4m3_pos(v);
                            int byte = trow * 512 + (((slotbase + j * 2) ^ swz) << 4) + sub;
                            *(_Float16*)((char*)smem + byte) = q;
                        }
                    }
                }
            }
            __syncthreads();
#pragma unroll
            for (int cch = 0; cch < 8; cch++) {
                int flat = cch * 512 + tid;          // 16B-chunk index, 4096/half
                int row  = flat >> 5;                // 0..127
                int slot = flat & 31;
                int swz  = (row & 7) ^ ((row >> 3) & 1);
                f16x8 v8 = *(const f16x8*)((char*)smem + row * 512 + ((slot ^ swz) << 4));
                *(f16x8*)(Cq + (size_t)(m0 + half * 128 + row) * N + n0 + slot * 8) = v8;
            }
            if (half == 0) __syncthreads();
        }
    } else {
        const int row0 = m0 + wr * 128 + kq * 4;
        float* C = (float*)Cv;
#pragma unroll
        for (int j = 0; j < 4; j++) {
            const float bq = (float)(_Float16)bias[col0 + j * 16];
#pragma unroll
            for (int i = 0; i < 8; i++) {
                size_t base = (size_t)(row0 + i * 16) * N + (col0 + j * 16);
#pragma unroll
                for (int r = 0; r < 4; r++) {
                    float v = acc[i][j][r] + bq;
                    C[base + (size_t)r * N] = (float)(_Float16)v;
                }
            }
        }
    }
}

extern "C" void kernel_launch(void* const* d_in, const int* in_sizes, int n_in,
                              void* d_out, int out_size, void* d_ws, size_t ws_size,
                              hipStream_t stream) {
    const float* x  = (const float*)d_in[0];   // [16384,1024]
    const float* w1 = (const float*)d_in[1];   // [4096,1024]
    const float* b1 = (const float*)d_in[2];   // [4096]
    const float* w2 = (const float*)d_in[3];   // [1024,4096]
    const float* b2 = (const float*)d_in[4];   // [1024]
    float* out = (float*)d_out;

    // workspace layout (bytes):
    // hq  f16 [16384,4096] : 134,217,728
    // xh  f16 [16384,1024] :  33,554,432
    // w1h f16 [4096,1024]  :   8,388,608
    // wq  f16 [1024,4096]  :   8,388,608
    const size_t need = 134217728ull + 33554432ull + 2ull * 8388608ull;
    if (ws_size < need) return;  // fail visibly (output stays zero)

    char* ws = (char*)d_ws;
    _Float16* hq  = (_Float16*)ws;
    _Float16* xh  = (_Float16*)(ws + 134217728ull);
    _Float16* w1h = xh + 16777216;
    _Float16* wq  = w1h + 4194304;

    cvt_f16_kernel<<<16384, 256, 0, stream>>>(x, xh, 4194304);
    cvt_f16_kernel<<<4096, 256, 0, stream>>>(w1, w1h, 1048576);
    quant_e4m3_kernel<<<4096, 256, 0, stream>>>(w2, wq, 1048576);

    // GEMM1: M=16384, N=4096, K=1024 -> grid (16,64) = 1024 wg
    gemm_ffn<D_DIM, H_DIM, true ><<<dim3(H_DIM / 256, M_TOT / 256), 512, 0, stream>>>(xh, w1h, b1, hq);
    // GEMM2: M=16384, N=1024, K=4096 -> grid (4,64) = 256 wg (1 per CU)
    gemm_ffn<H_DIM, D_DIM, false><<<dim3(D_DIM / 256, M_TOT / 256), 512, 0, stream>>>(hq, wq, b2, out);
}

// Round 6
// 246.169 us; speedup vs baseline: 2.3229x; 2.3229x over previous
//
#include <hip/hip_runtime.h>
#include <stdint.h>

// FFN: x[16384,1024] -> relu(x@W1^T+b1)[16384,4096] -> q_e4m3 -> @W2^T+b2 -> q_e5m10
// Round 8: GEMM2 on the MX-fp8 pipe. A(=hq) and B(=wq) are EXACT e4m3 values,
// so mfma_scale_f32_16x16x128_f8f6f4 with unit scales (e8m0 0x7F) computes
// exact products with fp32 accumulation — numerically equivalent to the f16
// path (sum-order noise << existing 0.0234 absmax from GEMM1's f16 rounding).
// Halves GEMM2's MFMA cycles, LDS reads, staged bytes, and GEMM1's hq write.
// hq/wq now stored as e4m3 BYTES; GEMM1 epilogue converts its exact-e4m3-f16
// LDS tile to bytes via v_cvt_pk_fp8_f32 (identity on e4m3 values; HW RNE on
// the OCP grid == reference float_quantize grid for |x| <= 240).
// GEMM1 K-loop = round-4 structure (best measured, 156us). Round-5's
// A-direct-from-global is reverted (VMEM per-lane path regressed 2x).

#define M_TOT 16384
#define D_DIM 1024
#define H_DIM 4096

typedef _Float16 f16x8 __attribute__((ext_vector_type(8)));
typedef _Float16 f16x4 __attribute__((ext_vector_type(4)));
typedef float f32x4 __attribute__((ext_vector_type(4)));
typedef int i32x4 __attribute__((ext_vector_type(4)));
typedef int i32x8 __attribute__((ext_vector_type(8)));

// global -> LDS direct copy, 16B per lane. LDS dest = wave-uniform base + lane*16.
__device__ __forceinline__ void gl16(const void* g, void* l) {
    __builtin_amdgcn_global_load_lds(
        (const __attribute__((address_space(1))) unsigned int*)(uintptr_t)g,
        (__attribute__((address_space(3))) unsigned int*)(unsigned int)(uintptr_t)l,
        16, 0, 0);
}

// positive-input e4m3 quantize (post-relu), division-free, RNE. Returns the
// quantized VALUE as f16 (exactly representable).
__device__ __forceinline__ _Float16 q_e4m3_pos(float v) {
    uint32_t t = __float_as_uint(v);
    uint32_t tn = (t + 0x7ffffu + ((t >> 20) & 1u)) & 0xfff00000u;
    float qn = __uint_as_float(tn);
    float qs = rintf(v * 512.0f) * 0.001953125f;
    return (_Float16)(v < 0.015625f ? qs : qn);
}

// ---- pre-pass: fp32 -> f16 (RNE), vectorized x4 ----
__global__ __launch_bounds__(256) void cvt_f16_kernel(
    const float* __restrict__ in, _Float16* __restrict__ out, int n4)
{
    int i = blockIdx.x * 256 + threadIdx.x;
    if (i >= n4) return;
    float4 v = reinterpret_cast<const float4*>(in)[i];
    f16x4 hv = {(_Float16)v.x, (_Float16)v.y, (_Float16)v.z, (_Float16)v.w};
    reinterpret_cast<f16x4*>(out)[i] = hv;
}

// ---- pre-pass: fp32 -> e4m3 BYTES via HW cvt (RNE, OCP grid == ref grid) ----
__global__ __launch_bounds__(256) void quant_e4m3_byte_kernel(
    const float* __restrict__ in, uint32_t* __restrict__ outq, int n4)
{
    int i = blockIdx.x * 256 + threadIdx.x;
    if (i >= n4) return;
    float4 v = reinterpret_cast<const float4*>(in)[i];
    uint32_t r = __builtin_amdgcn_cvt_pk_fp8_f32(v.x, v.y, 0, false);
    r = __builtin_amdgcn_cvt_pk_fp8_f32(v.z, v.w, r, true);
    outq[i] = r;
}

// ---- GEMM1: h=relu(xh@w1h^T+b1), q_e4m3, store BYTES. 256x256 BK=64 f16. ----
// Round-4 barrier-light K-loop (best measured). Epilogue: q_e4m3 -> f16 LDS
// transpose tile (swizzled) -> cvt to e4m3 bytes on coalesced store.
__global__ __launch_bounds__(512) void gemm1_f16(
    const _Float16* __restrict__ A, const _Float16* __restrict__ B,
    const float* __restrict__ bias, uint8_t* __restrict__ Cq)
{
    constexpr int K = D_DIM;   // 1024
    constexpr int N = H_DIM;   // 4096 (bytes per out row)
    __shared__ __align__(16) _Float16 smem[65536];   // 128 KiB
    _Float16* sA = smem;            // 2 x 16384
    _Float16* sB = smem + 32768;    // 2 x 16384

    const int tid  = threadIdx.x;
    const int lane = tid & 63;
    const int w    = tid >> 6;
    const int wr   = w >> 2, wc = w & 3;
    const int fr   = lane & 15, kq = lane >> 4;

    constexpr int NBX = N / 256;               // 16
    constexpr int NWG = (M_TOT / 256) * NBX;   // 1024
    constexpr int CPX = NWG / 8;
    int bid = blockIdx.y * NBX + blockIdx.x;
    bid = (bid & 7) * CPX + (bid >> 3);
    const int n0 = (bid % NBX) * 256;
    const int m0 = (bid / NBX) * 256;

    const int srow = tid >> 3;
    const int sseg = (tid & 7) ^ (srow & 7);
    const _Float16* gA = A + (size_t)(m0 + srow) * K + sseg * 8;
    const _Float16* gB = B + (size_t)(n0 + srow) * K + sseg * 8;
    const int ldsw = w * 512;
    const size_t R1 = (size_t)64 * K, R2 = (size_t)128 * K, R3 = (size_t)192 * K;

    const int xorv = fr & 7;
    const int cA0 = (kq ^ xorv) * 8;
    const int cA1 = ((kq + 4) ^ xorv) * 8;
    const int aRow = wr * 128 + fr;
    const int bRow = wc * 64 + fr;

    f32x4 acc[8][4];
#pragma unroll
    for (int i = 0; i < 8; i++)
#pragma unroll
        for (int j = 0; j < 4; j++) acc[i][j] = (f32x4){0.f, 0.f, 0.f, 0.f};

    f16x8 bfr[4][2];
    constexpr int NK = K / 64;   // 16

    gl16(gB,      sB + ldsw);
    gl16(gB + R1, sB + 4096 + ldsw);
    gl16(gB + R2, sB + 8192 + ldsw);
    gl16(gB + R3, sB + 12288 + ldsw);
    gl16(gA,      sA + ldsw);
    gl16(gA + R1, sA + 4096 + ldsw);
    gl16(gA + R2, sA + 8192 + ldsw);
    gl16(gA + R3, sA + 12288 + ldsw);
    asm volatile("s_waitcnt vmcnt(0)" ::: "memory");
    __builtin_amdgcn_s_barrier();
    asm volatile("" ::: "memory");

    for (int t = 0; t < NK; ++t) {
        const int c = t & 1;
        const _Float16* sAc = sA + c * 16384;
        const _Float16* sBc = sB + c * 16384;
        _Float16* sAn = sA + (c ^ 1) * 16384;
        _Float16* sBn = sB + (c ^ 1) * 16384;
        const bool pref = (t + 1 < NK);

        if (pref) {
            const _Float16* gAn = gA + (size_t)(t + 1) * 64;
            const _Float16* gBn = gB + (size_t)(t + 1) * 64;
            gl16(gBn,      sBn + ldsw);
            gl16(gBn + R1, sBn + 4096 + ldsw);
            gl16(gBn + R2, sBn + 8192 + ldsw);
            gl16(gBn + R3, sBn + 12288 + ldsw);
            gl16(gAn,      sAn + ldsw);
            gl16(gAn + R1, sAn + 4096 + ldsw);
            gl16(gAn + R2, sAn + 8192 + ldsw);
            gl16(gAn + R3, sAn + 12288 + ldsw);
        }

#pragma unroll
        for (int p = 0; p < 4; ++p) {
            f16x8 afr[2][2];
#pragma unroll
            for (int ii = 0; ii < 2; ii++) {
                const _Float16* ra = sAc + (aRow + (2 * p + ii) * 16) * 64;
                afr[ii][0] = *(const f16x8*)(ra + cA0);
                afr[ii][1] = *(const f16x8*)(ra + cA1);
            }
            if (p == 0) {
#pragma unroll
                for (int j = 0; j < 4; j++) {
                    const _Float16* rb = sBc + (bRow + j * 16) * 64;
                    bfr[j][0] = *(const f16x8*)(rb + cA0);
                    bfr[j][1] = *(const f16x8*)(rb + cA1);
                }
            }
            __builtin_amdgcn_s_setprio(1);
#pragma unroll
            for (int ii = 0; ii < 2; ii++)
#pragma unroll
                for (int j = 0; j < 4; j++) {
                    acc[2*p+ii][j] = __builtin_amdgcn_mfma_f32_16x16x32_f16(
                        afr[ii][0], bfr[j][0], acc[2*p+ii][j], 0, 0, 0);
                    acc[2*p+ii][j] = __builtin_amdgcn_mfma_f32_16x16x32_f16(
                        afr[ii][1], bfr[j][1], acc[2*p+ii][j], 0, 0, 0);
                }
            __builtin_amdgcn_s_setprio(0);
        }

        asm volatile("s_waitcnt vmcnt(0)" ::: "memory");
        __builtin_amdgcn_s_barrier();
        asm volatile("" ::: "memory");
    }

    // epilogue: +bias, relu, q_e4m3 (f16 value) -> swizzled LDS [256][256] f16
    // tile -> read f16x8, convert to 8 e4m3 bytes (exact), coalesced 8B stores.
    const int col0 = n0 + wc * 64 + fr;
    float bv[4];
#pragma unroll
    for (int j = 0; j < 4; j++) bv[j] = bias[col0 + j * 16];
    const int sub = (fr & 7) * 2;
    const int slotbase = wc * 8 + (fr >> 3);
    const int rowbase = wr * 128 + kq * 4;
#pragma unroll
    for (int i = 0; i < 8; i++) {
        const int trow0 = rowbase + i * 16;
#pragma unroll
        for (int r = 0; r < 4; r++) {
            const int trow = trow0 + r;
            const int swz = (((kq & 1) * 4 + r)) ^ (kq >> 1);  // == (trow&7)^((trow>>3)&1)
#pragma unroll
            for (int j = 0; j < 4; j++) {
                float v = fmaxf(acc[i][j][r] + bv[j], 0.0f);
                _Float16 q = q_e4m3_pos(v);
                int byte = trow * 512 + (((slotbase + j * 2) ^ swz) << 4) + sub;
                *(_Float16*)((char*)smem + byte) = q;
            }
        }
    }
    __syncthreads();
#pragma unroll
    for (int cch = 0; cch < 16; cch++) {
        int flat = cch * 512 + tid;
        int row  = flat >> 5;
        int slot = flat & 31;
        int swz  = (row & 7) ^ ((row >> 3) & 1);
        f16x8 v8 = *(const f16x8*)((char*)smem + row * 512 + ((slot ^ swz) << 4));
        uint32_t u0 = __builtin_amdgcn_cvt_pk_fp8_f32((float)v8[0], (float)v8[1], 0, false);
        u0 = __builtin_amdgcn_cvt_pk_fp8_f32((float)v8[2], (float)v8[3], u0, true);
        uint32_t u1 = __builtin_amdgcn_cvt_pk_fp8_f32((float)v8[4], (float)v8[5], 0, false);
        u1 = __builtin_amdgcn_cvt_pk_fp8_f32((float)v8[6], (float)v8[7], u1, true);
        uint2 u = {u0, u1};
        *(uint2*)(Cq + (size_t)(m0 + row) * N + n0 + slot * 8) = u;
    }
}

// ---- GEMM2: out = hq @ wq^T + b2q (MX-fp8, unit scales), q_e5m10, fp32 out ----
// A[16384,4096] bytes, B[1024,4096] bytes, NT. 256x256 tile, BK=128 bytes.
// Same 128B-row staging geometry + swizzle as the f16 kernel. Round-4 schedule.
__global__ __launch_bounds__(512) void gemm2_fp8(
    const uint8_t* __restrict__ A, const uint8_t* __restrict__ B,
    const float* __restrict__ b2, float* __restrict__ C)
{
    constexpr int Kb = H_DIM;  // 4096 bytes per row
    constexpr int N  = D_DIM;  // 1024
    __shared__ __align__(16) uint8_t smem[131072];
    uint8_t* sA = smem;            // 2 x 32768
    uint8_t* sB = smem + 65536;    // 2 x 32768

    const int tid  = threadIdx.x;
    const int lane = tid & 63;
    const int w    = tid >> 6;
    const int wr   = w >> 2, wc = w & 3;
    const int fr   = lane & 15, kq = lane >> 4;

    constexpr int NBX = N / 256;               // 4
    constexpr int NWG = (M_TOT / 256) * NBX;   // 256
    constexpr int CPX = NWG / 8;
    int bid = blockIdx.y * NBX + blockIdx.x;
    bid = (bid & 7) * CPX + (bid >> 3);
    const int n0 = (bid % NBX) * 256;
    const int m0 = (bid / NBX) * 256;

    // staging: round = 64 rows x 128B = 8KB; 4 rounds per operand per tile.
    const int srow = tid >> 3;
    const int sseg = (tid & 7) ^ (srow & 7);     // 16B-slot pre-swizzle
    const uint8_t* gA = A + (size_t)(m0 + srow) * Kb + sseg * 16;
    const uint8_t* gB = B + (size_t)(n0 + srow) * Kb + sseg * 16;
    const int ldsw = w * 1024;                   // bytes per wave per round
    const size_t R1 = (size_t)64 * Kb, R2 = (size_t)128 * Kb, R3 = (size_t)192 * Kb;

    // fragment reads: lane covers bytes [kq*32, kq*32+31] of its row ->
    // 16B slots 2kq, 2kq+1, each XOR'd with (row&7) == (fr&7).
    const int xorv = fr & 7;
    const int sO0 = ((2 * kq) ^ xorv) * 16;
    const int sO1 = ((2 * kq + 1) ^ xorv) * 16;
    const int aRowB = (wr * 128 + fr) * 128;     // byte base of lane's A row
    const int bRowB = (wc * 64 + fr) * 128;

    f32x4 acc[8][4];
#pragma unroll
    for (int i = 0; i < 8; i++)
#pragma unroll
        for (int j = 0; j < 4; j++) acc[i][j] = (f32x4){0.f, 0.f, 0.f, 0.f};

    i32x8 bfr[4];
    constexpr int NK = Kb / 128;   // 32
    constexpr uint32_t SC1 = 0x7f7f7f7fu;   // e8m0 unit scale in every byte

    gl16(gB,      sB + ldsw);
    gl16(gB + R1, sB + 8192 + ldsw);
    gl16(gB + R2, sB + 16384 + ldsw);
    gl16(gB + R3, sB + 24576 + ldsw);
    gl16(gA,      sA + ldsw);
    gl16(gA + R1, sA + 8192 + ldsw);
    gl16(gA + R2, sA + 16384 + ldsw);
    gl16(gA + R3, sA + 24576 + ldsw);
    asm volatile("s_waitcnt vmcnt(0)" ::: "memory");
    __builtin_amdgcn_s_barrier();
    asm volatile("" ::: "memory");

    for (int t = 0; t < NK; ++t) {
        const int c = t & 1;
        const uint8_t* sAc = sA + c * 32768;
        const uint8_t* sBc = sB + c * 32768;
        uint8_t* sAn = sA + (c ^ 1) * 32768;
        uint8_t* sBn = sB + (c ^ 1) * 32768;
        const bool pref = (t + 1 < NK);

        if (pref) {
            const uint8_t* gAn = gA + (size_t)(t + 1) * 128;
            const uint8_t* gBn = gB + (size_t)(t + 1) * 128;
            gl16(gBn,      sBn + ldsw);
            gl16(gBn + R1, sBn + 8192 + ldsw);
            gl16(gBn + R2, sBn + 16384 + ldsw);
            gl16(gBn + R3, sBn + 24576 + ldsw);
            gl16(gAn,      sAn + ldsw);
            gl16(gAn + R1, sAn + 8192 + ldsw);
            gl16(gAn + R2, sAn + 16384 + ldsw);
            gl16(gAn + R3, sAn + 24576 + ldsw);
        }

#pragma unroll
        for (int p = 0; p < 4; ++p) {
            i32x8 af[2];
#pragma unroll
            for (int ii = 0; ii < 2; ii++) {
                const uint8_t* ra = sAc + aRowB + (2 * p + ii) * 2048;
                i32x4 lo = *(const i32x4*)(ra + sO0);
                i32x4 hi = *(const i32x4*)(ra + sO1);
                af[ii] = (i32x8){lo.x, lo.y, lo.z, lo.w, hi.x, hi.y, hi.z, hi.w};
            }
            if (p == 0) {
#pragma unroll
                for (int j = 0; j < 4; j++) {
                    const uint8_t* rb = sBc + bRowB + j * 2048;
                    i32x4 lo = *(const i32x4*)(rb + sO0);
                    i32x4 hi = *(const i32x4*)(rb + sO1);
                    bfr[j] = (i32x8){lo.x, lo.y, lo.z, lo.w, hi.x, hi.y, hi.z, hi.w};
                }
            }
            __builtin_amdgcn_s_setprio(1);
#pragma unroll
            for (int ii = 0; ii < 2; ii++)
#pragma unroll
                for (int j = 0; j < 4; j++) {
                    acc[2*p+ii][j] = __builtin_amdgcn_mfma_scale_f32_16x16x128_f8f6f4(
                        af[ii], bfr[j], acc[2*p+ii][j],
                        0, 0,            // cbsz=FP8, blgp=FP8
                        0, SC1,          // opsel_a, scale_a (1.0)
                        0, SC1);         // opsel_b, scale_b (1.0)
                }
            __builtin_amdgcn_s_setprio(0);
        }

        asm volatile("s_waitcnt vmcnt(0)" ::: "memory");
        __builtin_amdgcn_s_barrier();
        asm volatile("" ::: "memory");
    }

    // epilogue: + q_e5m10(b2), quantize e5m10 (f16 RNE roundtrip), store fp32
    const int col0 = n0 + wc * 64 + fr;
    const int row0 = m0 + wr * 128 + kq * 4;
#pragma unroll
    for (int j = 0; j < 4; j++) {
        const float bq = (float)(_Float16)b2[col0 + j * 16];
#pragma unroll
        for (int i = 0; i < 8; i++) {
            size_t base = (size_t)(row0 + i * 16) * N + (col0 + j * 16);
#pragma unroll
            for (int r = 0; r < 4; r++) {
                float v = acc[i][j][r] + bq;
                C[base + (size_t)r * N] = (float)(_Float16)v;
            }
        }
    }
}

extern "C" void kernel_launch(void* const* d_in, const int* in_sizes, int n_in,
                              void* d_out, int out_size, void* d_ws, size_t ws_size,
                              hipStream_t stream) {
    const float* x  = (const float*)d_in[0];   // [16384,1024]
    const float* w1 = (const float*)d_in[1];   // [4096,1024]
    const float* b1 = (const float*)d_in[2];   // [4096]
    const float* w2 = (const float*)d_in[3];   // [1024,4096]
    const float* b2 = (const float*)d_in[4];   // [1024]
    float* out = (float*)d_out;

    // workspace layout (bytes):
    // hq  e4m3 bytes [16384,4096] :  67,108,864
    // xh  f16 [16384,1024]        :  33,554,432
    // w1h f16 [4096,1024]         :   8,388,608
    // wq  e4m3 bytes [1024,4096]  :   4,194,304
    const size_t need = 67108864ull + 33554432ull + 8388608ull + 4194304ull;
    if (ws_size < need) return;  // fail visibly (output stays zero)

    char* ws = (char*)d_ws;
    uint8_t*  hq  = (uint8_t*)ws;
    _Float16* xh  = (_Float16*)(ws + 67108864ull);
    _Float16* w1h = xh + 16777216;
    uint8_t*  wq  = (uint8_t*)(w1h + 4194304);

    cvt_f16_kernel<<<16384, 256, 0, stream>>>(x, xh, 4194304);
    cvt_f16_kernel<<<4096, 256, 0, stream>>>(w1, w1h, 1048576);
    quant_e4m3_byte_kernel<<<4096, 256, 0, stream>>>(w2, (uint32_t*)wq, 1048576);

    // GEMM1: M=16384, N=4096, K=1024 -> grid (16,64) = 1024 wg
    gemm1_f16<<<dim3(H_DIM / 256, M_TOT / 256), 512, 0, stream>>>(xh, w1h, b1, hq);
    // GEMM2: M=16384, N=1024, K=4096 bytes -> grid (4,64) = 256 wg
    gemm2_fp8<<<dim3(D_DIM / 256, M_TOT / 256), 512, 0, stream>>>(hq, wq, b2, out);
}